// Round 11
// baseline (632.809 us; speedup 1.0000x reference)
//
#include <hip/hip_runtime.h>
#include <hip/hip_bf16.h>

#define HIDDEN 128
#define DEPTH 4
#define INTER 512
#define NSTATE 16
#define DT_RANK 8
#define EPS_RMS 1e-5f
#define MTOK 512            // B*T
#define KIN 150528

typedef __attribute__((ext_vector_type(8))) short bf16x8;
typedef __attribute__((ext_vector_type(4))) float f32x4;

__device__ __forceinline__ unsigned short f2bf(float f) {
  unsigned int u = __builtin_bit_cast(unsigned int, f);
  u += 0x7fffu + ((u >> 16) & 1u);
  return (unsigned short)(u >> 16);
}
__device__ __forceinline__ float silu_f(float x) {
  return x / (1.0f + __expf(-x));
}
__device__ __forceinline__ float f4sum(f32x4 v) {
  return (v.x + v.y) + (v.z + v.w);
}

// ---------------------------------------------------------------------------
// zero_part: 4 MB partial buffer zero (1024 x 256 x float4).
// ---------------------------------------------------------------------------
__global__ __launch_bounds__(256) void zero_part(float* __restrict__ p)
{
  const size_t i = (size_t)blockIdx.x * 256 + threadIdx.x;
  ((float4*)p)[i] = (float4){0.f, 0.f, 0.f, 0.f};
}

// ---------------------------------------------------------------------------
// Projection GEMM v3 (R3-proven, ~78 us): zero-duplication tiling.
// ---------------------------------------------------------------------------
__global__ __launch_bounds__(512) void proj_gemm(
    const float* __restrict__ x, const float* __restrict__ w,
    float* __restrict__ partial)
{
  const int bid = blockIdx.x;          // 0..255
  const int mb = (bid >> 3) & 3;       // 0..3  (M-tile of 128 rows)
  const int kb = (bid & 7) + (bid >> 5) * 8;   // 0..63 (XCD-clustered)
  const int nchunk = 18 + (kb < 24 ? 1 : 0);
  const int c0 = kb * 18 + (kb < 24 ? kb : 24);

  __shared__ char sm[256 * 256];       // 256 rows (x:0-127, w:128-255) x 256 B

  const int tid = threadIdx.x;
  const int lane = tid & 63;
  const int wv = tid >> 6;             // 0..7
  const int wm2 = wv >> 2;             // 0..1  M-half (64 rows)
  const int wn4 = wv & 3;              // 0..3  N-quarter (32 cols)
  const int fr = lane & 15;
  const int kq = lane >> 4;            // 0..3
  const int l31 = lane & 31;
  const int rpar = lane >> 5;          // 0/1

  const float* gptr = (wv < 4)
      ? (x + (size_t)(mb * 128 + wv * 32 + rpar) * KIN + l31 * 4)
      : (w + (size_t)((wv - 4) * 32 + rpar) * KIN + l31 * 4);

  f32x4 acc[4][2];
  #pragma unroll
  for (int mi = 0; mi < 4; ++mi) {
    acc[mi][0] = (f32x4){0.f, 0.f, 0.f, 0.f};
    acc[mi][1] = (f32x4){0.f, 0.f, 0.f, 0.f};
  }

  float4 rv[16];
  {
    const float* base = gptr + (size_t)c0 * 128;
    #pragma unroll
    for (int j = 0; j < 16; ++j)
      rv[j] = *(const float4*)(base + (size_t)(j * 2) * KIN);
  }

  for (int cc = 0; cc < nchunk; ++cc) {
    #pragma unroll
    for (int j = 0; j < 16; ++j) {
      const int r = wv * 32 + j * 2 + rpar;
      const int phys = (l31 * 8) ^ ((r & 7) << 4);
      ushort4 bq = {f2bf(rv[j].x), f2bf(rv[j].y), f2bf(rv[j].z), f2bf(rv[j].w)};
      *(ushort4*)(sm + r * 256 + phys) = bq;
    }
    __syncthreads();
    if (cc + 1 < nchunk) {
      const float* base = gptr + (size_t)(c0 + cc + 1) * 128;
      #pragma unroll
      for (int j = 0; j < 16; ++j)
        rv[j] = *(const float4*)(base + (size_t)(j * 2) * KIN);
    }
    #pragma unroll
    for (int ks = 0; ks < 4; ++ks) {
      const int log = ks * 64 + kq * 16;
      bf16x8 a[4];
      #pragma unroll
      for (int mi = 0; mi < 4; ++mi) {
        const int row = wm2 * 64 + mi * 16 + fr;
        a[mi] = *(const bf16x8*)(sm + row * 256 + (log ^ ((row & 7) << 4)));
      }
      #pragma unroll
      for (int ni = 0; ni < 2; ++ni) {
        const int row = 128 + wn4 * 32 + ni * 16 + fr;
        const bf16x8 b = *(const bf16x8*)(sm + row * 256 + (log ^ ((row & 7) << 4)));
        #pragma unroll
        for (int mi = 0; mi < 4; ++mi)
          acc[mi][ni] = __builtin_amdgcn_mfma_f32_16x16x32_bf16(a[mi], b, acc[mi][ni], 0, 0, 0);
      }
    }
    __syncthreads();
  }
  float* hp = partial + (size_t)(kb & 15) * (MTOK * HIDDEN);
  #pragma unroll
  for (int mi = 0; mi < 4; ++mi)
    #pragma unroll
    for (int ni = 0; ni < 2; ++ni)
      #pragma unroll
      for (int r = 0; r < 4; ++r) {
        const int row = mb * 128 + wm2 * 64 + mi * 16 + kq * 4 + r;
        const int col = wn4 * 32 + ni * 16 + fr;
        atomicAdd(hp + (size_t)row * HIDDEN + col, acc[mi][ni][r]);
      }
}

// ---------------------------------------------------------------------------
// fconv: [h-window via part-sum (mode 0) or out_proj+res (mode 1)] + rms +
// in_proj + conv + x_proj + dt, all in one dispatch via 3-token redundant
// halo compute (R8 structure, R9 layouts). Row-stationary weight reads:
// each opw/ipw row read ONCE per block, dotted against all 5 window tokens.
// h/gate double-buffered (hin/hout, gin/gout) to avoid same-dispatch races.
// uG/dtG token-major, yT channel-major: amplification-free writes (R9).
// grid 256 (2 own tokens + 3 halo), block 512.
// ---------------------------------------------------------------------------
__global__ __launch_bounds__(512) void fconv(
    int mode,
    const float* __restrict__ part, const float* __restrict__ pb,
    const float* __restrict__ yT, const float* __restrict__ gin,
    const float* __restrict__ hin, float* __restrict__ hout,
    float* __restrict__ gout,
    const float* __restrict__ opw,   // layer l (mode 1)
    const float* __restrict__ nw,    // norm row for layer lw
    const float* __restrict__ ipw,   // layer lw
    const float* __restrict__ cw, const float* __restrict__ cb,
    const float* __restrict__ xpw,
    const float* __restrict__ dtw, const float* __restrict__ dtb,
    float* __restrict__ uG, float* __restrict__ dtG,
    float* __restrict__ Bm, float* __restrict__ Cm)
{
  const int m0 = blockIdx.x * 2;
  const int b = m0 >> 8, tb0 = m0 & 255;
  const int tid = threadIdx.x;

  __shared__ float y2hs[5 * 512];      // y2, then reused as hs rows
  __shared__ float hrow[5 * 128];
  __shared__ float hn[5 * 128];
  __shared__ float u_loc[2 * 512];
  __shared__ float si[2 * 40];

  if (mode == 0) {
    // h window from part-sum (5 tokens; write own 2 to hout)
    for (int o = tid; o < 640; o += 512) {
      const int j = o >> 7, d = o & 127;
      const int wt = tb0 - 3 + j;
      float hv = 0.f;
      if (wt >= 0) {
        const int gt = b * 256 + wt;
        hv = pb[d];
        #pragma unroll
        for (int s = 0; s < 16; ++s)
          hv += part[(size_t)s * (MTOK * HIDDEN) + (size_t)gt * 128 + d];
        if (j >= 3) hout[(size_t)gt * 128 + d] = hv;
      }
      hrow[j * 128 + d] = hv;
    }
  } else {
    // stage y2 = y * silu(gate) for the 5-token window
    for (int o = tid; o < 2560; o += 512) {
      const int j = o >> 9, i = o & 511;
      const int wt = tb0 - 3 + j;
      float v = 0.f;
      if (wt >= 0) {
        const int gt = b * 256 + wt;
        v = yT[((size_t)b * 512 + i) * 256 + wt] *
            silu_f(gin[(size_t)gt * 512 + i]);
      }
      y2hs[j * 512 + i] = v;
    }
    __syncthreads();
    // out_proj row-stationary: thread (d, kq), one opw row-quarter, 5 tokens
    {
      const int d = tid >> 2, kq = tid & 3;
      const f32x4* wp = (const f32x4*)(opw + (size_t)d * 512 + kq * 128);
      f32x4 acc[5];
      #pragma unroll
      for (int j = 0; j < 5; ++j) acc[j] = (f32x4){0.f, 0.f, 0.f, 0.f};
      #pragma unroll
      for (int kk = 0; kk < 32; ++kk) {
        const f32x4 wv4 = wp[kk];
        #pragma unroll
        for (int j = 0; j < 5; ++j)
          acc[j] += ((const f32x4*)(y2hs + j * 512 + kq * 128))[kk] * wv4;
      }
      #pragma unroll
      for (int j = 0; j < 5; ++j) {
        float a = f4sum(acc[j]);
        a += __shfl_xor(a, 1); a += __shfl_xor(a, 2);
        if (kq == 0) {
          const int wt = tb0 - 3 + j;
          if (wt >= 0) {
            const int gt = b * 256 + wt;
            const float hv = hin[(size_t)gt * 128 + d] + a;
            hrow[j * 128 + d] = hv;
            if (j >= 3) hout[(size_t)gt * 128 + d] = hv;
          } else hrow[j * 128 + d] = 0.f;
        }
      }
    }
  }
  __syncthreads();
  // rmsnorm for 5 tokens (waves 0..4)
  {
    const int wv = tid >> 6, ln = tid & 63;
    if (wv < 5) {
      const float v0 = hrow[wv * 128 + ln], v1 = hrow[wv * 128 + ln + 64];
      float ss = v0 * v0 + v1 * v1;
      #pragma unroll
      for (int off = 1; off < 64; off <<= 1) ss += __shfl_xor(ss, off);
      const float rr = rsqrtf(ss * (1.0f / 128.0f) + EPS_RMS);
      hn[wv * 128 + ln]      = v0 * rr * nw[ln];
      hn[wv * 128 + ln + 64] = v1 * rr * nw[ln + 64];
    }
  }
  __syncthreads();
  // in_proj row-stationary: thread owns rows {tid, tid+512}, dots 5 tokens.
  // hs rows (e<512) -> y2hs (reused); gate rows (e>=512) -> gout, own 2 only.
  #pragma unroll
  for (int jj = 0; jj < 2; ++jj) {
    const int e = tid + jj * 512;
    const f32x4* wp4 = (const f32x4*)(ipw + (size_t)e * 128);
    f32x4 acc[5];
    #pragma unroll
    for (int j = 0; j < 5; ++j) acc[j] = (f32x4){0.f, 0.f, 0.f, 0.f};
    #pragma unroll
    for (int kk = 0; kk < 32; ++kk) {
      const f32x4 wv4 = wp4[kk];
      #pragma unroll
      for (int j = 0; j < 5; ++j)
        acc[j] += ((const f32x4*)(hn + j * 128))[kk] * wv4;
    }
    if (jj == 0) {
      #pragma unroll
      for (int j = 0; j < 5; ++j) y2hs[j * 512 + tid] = f4sum(acc[j]);
    } else {
      gout[(size_t)m0 * 512 + tid]       = f4sum(acc[3]);
      gout[(size_t)(m0 + 1) * 512 + tid] = f4sum(acc[4]);
    }
  }
  __syncthreads();
  // conv + silu for own 2 tokens (token tb0+t uses hs rows t..t+3)
  #pragma unroll
  for (int jj = 0; jj < 2; ++jj) {
    const int o = tid + jj * 512;
    const int t = o >> 9, i = o & 511;
    const float4 c4v = *(const float4*)(cw + (size_t)i * 4);
    const float s = cb[i] + c4v.x * y2hs[t * 512 + i]
                          + c4v.y * y2hs[(t + 1) * 512 + i]
                          + c4v.z * y2hs[(t + 2) * 512 + i]
                          + c4v.w * y2hs[(t + 3) * 512 + i];
    const float uu = silu_f(s);
    u_loc[t * 512 + i] = uu;
    uG[((size_t)b * 256 + tb0 + t) * 512 + i] = uu;   // coalesced
  }
  __syncthreads();
  if (tid < 160) {                               // x_proj: 2 threads/output
    const int pid = tid >> 1, half = tid & 1;
    const int t = pid / 40, e = pid % 40;
    const float4* up = (const float4*)(u_loc + t * 512 + half * 256);
    const float4* wp = (const float4*)(xpw + (size_t)e * 512 + half * 256);
    float a0 = 0.f, a1 = 0.f, a2 = 0.f, a3 = 0.f;
    #pragma unroll 8
    for (int kk = 0; kk < 64; ++kk) {
      const float4 uv = up[kk], wv4 = wp[kk];
      a0 += uv.x * wv4.x; a1 += uv.y * wv4.y;
      a2 += uv.z * wv4.z; a3 += uv.w * wv4.w;
    }
    float a = (a0 + a1) + (a2 + a3);
    a += __shfl_xor(a, 1);
    if (half == 0) si[t * 40 + e] = a;
  }
  __syncthreads();
  if (tid < 64) {                                // B, C rows
    const int t = tid >> 5, q = tid & 31;
    if (q < 16) Bm[(size_t)(m0 + t) * 16 + q] = si[t * 40 + 8 + q];
    else        Cm[(size_t)(m0 + t) * 16 + (q - 16)] = si[t * 40 + 24 + (q - 16)];
  }
  #pragma unroll
  for (int jj = 0; jj < 2; ++jj) {               // dt softplus -> dtG (coalesced)
    const int o = tid + jj * 512;
    const int t = o >> 9, i = o & 511;
    float a0 = dtb[i];
    const float* dr = dtw + (size_t)i * 8;
    #pragma unroll
    for (int r = 0; r < 8; ++r) a0 += si[t * 40 + r] * dr[r];
    const float sp = (a0 > 20.f) ? a0 : log1pf(__expf(a0));
    dtG[((size_t)b * 256 + tb0 + t) * 512 + i] = sp;
  }
}

// ---------------------------------------------------------------------------
// fafin: out_proj(l=3) + residual + final rms -> out. grid 256, block 512.
// (R9 fusedA mode-2 path, standalone.)
// ---------------------------------------------------------------------------
__global__ __launch_bounds__(512) void fafin(
    const float* __restrict__ yT, const float* __restrict__ gin,
    const float* __restrict__ hin,
    const float* __restrict__ opw, const float* __restrict__ nwf,
    float* __restrict__ dout)
{
  const int m0 = blockIdx.x * 2;
  const int tid = threadIdx.x;
  const int o2 = tid >> 1;
  const int half = tid & 1;
  const int t = o2 >> 7, d = o2 & 127;
  __shared__ float y2[2][512];
  __shared__ float hrow[2][128];

  #pragma unroll
  for (int j = 0; j < 2; ++j) {
    const int o = tid + j * 512;
    const int tt = o >> 9, i = o & 511;
    const int gt = m0 + tt;
    const int b = gt >> 8, tb = gt & 255;
    const float yv = yT[((size_t)b * 512 + i) * 256 + tb];
    const float g  = gin[(size_t)gt * 512 + i];
    y2[tt][i] = yv * silu_f(g);
  }
  __syncthreads();
  const float4* yp = (const float4*)(&y2[t][0] + half * 256);
  const float4* wp = (const float4*)(opw + (size_t)d * 512 + half * 256);
  float a0 = 0.f, a1 = 0.f, a2 = 0.f, a3 = 0.f;
  #pragma unroll 8
  for (int kk = 0; kk < 64; ++kk) {
    const float4 yv = yp[kk], wv4 = wp[kk];
    a0 += yv.x * wv4.x; a1 += yv.y * wv4.y;
    a2 += yv.z * wv4.z; a3 += yv.w * wv4.w;
  }
  float a = (a0 + a1) + (a2 + a3);
  a += __shfl_xor(a, 1);
  const float hv = hin[(size_t)(m0 + t) * 128 + d] + a;
  if (half == 0) hrow[t][d] = hv;
  __syncthreads();
  {
    const int wvi = tid >> 6, ln = tid & 63;
    const int tt = wvi & 1;
    const float v0 = hrow[tt][ln], v1 = hrow[tt][ln + 64];
    float ss = v0 * v0 + v1 * v1;
    #pragma unroll
    for (int off = 1; off < 64; off <<= 1) ss += __shfl_xor(ss, off);
    const float rr = rsqrtf(ss * (1.0f / 128.0f) + EPS_RMS);
    if (wvi < 2) {
      dout[(size_t)(m0 + tt) * 128 + ln]      = v0 * rr * nwf[ln];
      dout[(size_t)(m0 + tt) * 128 + ln + 64] = v1 * rr * nwf[ln + 64];
    }
  }
}

// ---------------------------------------------------------------------------
// scan_k (R9-proven): chunked SSM scan. grid 1024, block 256.
// uG/dtG token-major (strided read from L2); yT channel-major (coalesced).
// ---------------------------------------------------------------------------
__global__ __launch_bounds__(256) void scan_k(
    const float* __restrict__ uG, const float* __restrict__ dtG,
    const float* __restrict__ Bm, const float* __restrict__ Cm,
    const float* __restrict__ Alog, const float* __restrict__ Dssm,
    float* __restrict__ yT)
{
  const int blk = blockIdx.x;       // 0..1023
  const int b = blk >> 9, i = blk & 511;
  const int tid = threadIdx.x;
  __shared__ float dt_r[256], u_r[256];
  __shared__ float B_l[256][17], C_l[256][17];
  __shared__ float e_l[16][17], P_l[16][17];
  dt_r[tid] = dtG[((size_t)b * 256 + tid) * 512 + i];
  u_r[tid]  = uG [((size_t)b * 256 + tid) * 512 + i];
  #pragma unroll
  for (int j = 0; j < 16; ++j) {
    const int o = tid + j * 256;
    B_l[o >> 4][o & 15] = Bm[(size_t)b * 4096 + o];
    C_l[o >> 4][o & 15] = Cm[(size_t)b * 4096 + o];
  }
  __syncthreads();
  const int c = tid >> 4, n = tid & 15;
  const float Av = -__expf(Alog[(size_t)i * 16 + n]);
  const float Dv = Dssm[i];
  float aj[16], xj[16];
  float s = 0.f, P = 1.f;
  #pragma unroll
  for (int j = 0; j < 16; ++j) {    // pass 1: local scan from 0
    const int t = c * 16 + j;
    const float dtv = dt_r[t];
    const float a = __expf(Av * dtv);
    const float xx = dtv * B_l[t][n] * u_r[t];
    aj[j] = a; xj[j] = xx;
    s = a * s + xx; P *= a;
  }
  e_l[c][n] = s; P_l[c][n] = P;
  __syncthreads();
  float s0 = 0.f;                   // stitch chunk prefixes
  for (int cc = 0; cc < c; ++cc)
    s0 = P_l[cc][n] * s0 + e_l[cc][n];
  s = s0;
  #pragma unroll
  for (int j = 0; j < 16; ++j) {    // pass 2: replay with true state
    const int t = c * 16 + j;
    s = aj[j] * s + xj[j];
    float p = s * C_l[t][n];
    p += __shfl_xor(p, 1); p += __shfl_xor(p, 2);
    p += __shfl_xor(p, 4); p += __shfl_xor(p, 8);
    if (n == 0)
      yT[((size_t)b * 512 + i) * 256 + t] = p + u_r[t] * Dv;  // coalesced
  }
}

extern "C" void kernel_launch(void* const* d_in, const int* in_sizes, int n_in,
                              void* d_out, int out_size, void* d_ws, size_t ws_size,
                              hipStream_t stream)
{
  (void)in_sizes; (void)n_in; (void)out_size; (void)ws_size;
  const float* x    = (const float*)d_in[0];
  const float* pw   = (const float*)d_in[1];
  const float* pb   = (const float*)d_in[2];
  const float* ipw  = (const float*)d_in[3];
  const float* cw   = (const float*)d_in[4];
  const float* cb   = (const float*)d_in[5];
  const float* xpw  = (const float*)d_in[6];
  const float* dtw  = (const float*)d_in[7];
  const float* dtb  = (const float*)d_in[8];
  const float* Alog = (const float*)d_in[9];
  const float* Dssm = (const float*)d_in[10];
  const float* opw  = (const float*)d_in[11];
  const float* nw   = (const float*)d_in[12];
  const float* nwf  = (const float*)d_in[13];
  float* out = (float*)d_out;

  float* ws   = (float*)d_ws;                 // ~10 MB scratch
  float* part = ws;                           // 16 * 65536 (atomic-accumulated)
  float* hA   = part + 16 * 65536;            // 65536
  float* hB   = hA + 65536;                   // 65536
  float* gA   = hB + 65536;                   // 262144
  float* gB   = gA + 262144;                  // 262144
  float* uG   = gB + 262144;                  // 262144 (token-major)
  float* dtG  = uG + 262144;                  // 262144 (token-major)
  float* Bm   = dtG + 262144;                 // 8192
  float* Cm   = Bm + 8192;                    // 8192
  float* yT   = Cm + 8192;                    // 262144 (channel-major)

  zero_part<<<dim3(1024), 256, 0, stream>>>(part);
  proj_gemm<<<dim3(256), 512, 0, stream>>>(x, pw, part);

  // A0CONV: h(window) from part + rms + in_proj(0) + conv(0) + xproj + dt
  fconv<<<dim3(256), 512, 0, stream>>>(
      0, part, pb, nullptr, nullptr, nullptr, hA, gA,
      nullptr, nw, ipw,
      cw, cb, xpw, dtw, dtb, uG, dtG, Bm, Cm);

  for (int l = 0; l < DEPTH; ++l) {
    scan_k<<<dim3(1024), 256, 0, stream>>>(
        uG, dtG, Bm, Cm, Alog + (size_t)l * 512 * 16, Dssm + (size_t)l * 512, yT);
    if (l < DEPTH - 1) {
      const float* hin  = (l & 1) ? hB : hA;
      float*       hout = (l & 1) ? hA : hB;
      const float* gin  = (l & 1) ? gB : gA;
      float*       gout = (l & 1) ? gA : gB;
      fconv<<<dim3(256), 512, 0, stream>>>(
          1, nullptr, nullptr, yT, gin, hin, hout, gout,
          opw + (size_t)l * 128 * 512,
          nw + (size_t)(l + 1) * 128,
          ipw + (size_t)(l + 1) * 1024 * 128,
          cw + (size_t)(l + 1) * 2048, cb + (size_t)(l + 1) * 512,
          xpw + (size_t)(l + 1) * 40 * 512,
          dtw + (size_t)(l + 1) * 512 * 8, dtb + (size_t)(l + 1) * 512,
          uG, dtG, Bm, Cm);
    } else {
      // l == 3: hin/gin are the buffers written by fconv(l=2): hB / gB
      fafin<<<dim3(256), 512, 0, stream>>>(
          yT, gB, hB, opw + (size_t)3 * 128 * 512, nwf, out);
    }
  }
}